// Round 1
// baseline (29060.794 us; speedup 1.0000x reference)
//
#include <hip/hip_runtime.h>
#include <math.h>

// GRU-modified: B=64, T=1024, I=256, H=512, fp32.
// Strategy R1:
//   - transpose recurrent weights once per launch (coalesced column reads)
//   - proj_gemm: hoisted input projections  ru_x -> ws, c_x -> d_out (overwritten later by h)
//   - gru_scan: one persistent WG per batch element (64 WGs, 512 thr), zero cross-WG sync;
//     streams WhT (2MB) + WrhT (1MB) from L2 every step.  This measures per-CU L2 BW.

#define B_ 64
#define T_ 1024
#define I_ 256
#define H_ 512

__device__ __forceinline__ float sigmoidf_(float x) { return 1.0f / (1.0f + expf(-x)); }

// ---------------- transpose: in [J][K] -> out [K][J] ----------------
__global__ void transpose_k(const float* __restrict__ in, float* __restrict__ out, int J, int K)
{
    __shared__ float tile[32][33];
    int k0 = blockIdx.x * 32, j0 = blockIdx.y * 32;
    int tx = threadIdx.x & 31, ty = threadIdx.x >> 5;   // 256 threads, ty 0..7
    #pragma unroll
    for (int r = ty; r < 32; r += 8)
        tile[r][tx] = in[(size_t)(j0 + r) * K + (k0 + tx)];
    __syncthreads();
    #pragma unroll
    for (int r = ty; r < 32; r += 8)
        out[(size_t)(k0 + r) * J + (j0 + tx)] = tile[tx][r];
}

// ---------------- input-projection GEMM ----------------
// out[m, n] = sum_k X[m,k] * W[n,k];  m in [0, B*T), n in [n_off, n_off + 64*gridDim.x)
// n < 1024 -> ru_x[m*1024 + n]   (Wx_ru rows)
// n >= 1024 -> c_x[m*512 + n-1024] (Wx_c rows), c_x lives in d_out's hidden area
#define BM 64
#define BN 64
#define BK 32
__launch_bounds__(256)
__global__ void proj_gemm(const float* __restrict__ X,
                          const float* __restrict__ Wru,   // [1024,256]
                          const float* __restrict__ Wc,    // [512,256]
                          float* __restrict__ ru_x,        // [B*T,1024]
                          float* __restrict__ c_x,         // [B*T,512]
                          int n_off)
{
    const int ntile = n_off + blockIdx.x * BN;
    const size_t m0 = (size_t)blockIdx.y * BM;
    const bool is_ru = ntile < 1024;

    __shared__ float As[BK][BM + 4];   // +4 pad keeps 16B row alignment, breaks bank stride
    __shared__ float Bs[BK][BN + 4];

    const int tid = threadIdx.x;
    const int tx = tid & 15, ty = tid >> 4;   // 16x16 thread grid, 4x4 outputs each
    float acc[4][4] = {};

    for (int k0 = 0; k0 < I_; k0 += BK) {
        #pragma unroll
        for (int l = 0; l < 2; ++l) {          // A tile: 64x32 = 512 float4s
            int q = tid * 2 + l;
            int r = q >> 3, c4 = (q & 7) * 4;
            float4 v = *(const float4*)(X + (m0 + r) * I_ + k0 + c4);
            As[c4 + 0][r] = v.x; As[c4 + 1][r] = v.y; As[c4 + 2][r] = v.z; As[c4 + 3][r] = v.w;
        }
        #pragma unroll
        for (int l = 0; l < 2; ++l) {          // B tile: 64(n) x 32(k)
            int q = tid * 2 + l;
            int n = q >> 3, c4 = (q & 7) * 4;
            const float* wp = is_ru ? (Wru + (size_t)(ntile + n) * I_)
                                    : (Wc  + (size_t)(ntile - 1024 + n) * I_);
            float4 v = *(const float4*)(wp + k0 + c4);
            Bs[c4 + 0][n] = v.x; Bs[c4 + 1][n] = v.y; Bs[c4 + 2][n] = v.z; Bs[c4 + 3][n] = v.w;
        }
        __syncthreads();
        #pragma unroll
        for (int kk = 0; kk < BK; ++kk) {
            float4 a = *(const float4*)&As[kk][ty * 4];
            float4 b = *(const float4*)&Bs[kk][tx * 4];
            acc[0][0] += a.x * b.x; acc[0][1] += a.x * b.y; acc[0][2] += a.x * b.z; acc[0][3] += a.x * b.w;
            acc[1][0] += a.y * b.x; acc[1][1] += a.y * b.y; acc[1][2] += a.y * b.z; acc[1][3] += a.y * b.w;
            acc[2][0] += a.z * b.x; acc[2][1] += a.z * b.y; acc[2][2] += a.z * b.z; acc[2][3] += a.z * b.w;
            acc[3][0] += a.w * b.x; acc[3][1] += a.w * b.y; acc[3][2] += a.w * b.z; acc[3][3] += a.w * b.w;
        }
        __syncthreads();
    }
    #pragma unroll
    for (int i = 0; i < 4; ++i) {
        size_t m = m0 + ty * 4 + i;
        float4 v = make_float4(acc[i][0], acc[i][1], acc[i][2], acc[i][3]);
        if (is_ru) *(float4*)(ru_x + m * 1024 + ntile + tx * 4) = v;
        else       *(float4*)(c_x  + m * 512  + (ntile - 1024) + tx * 4) = v;
    }
}

// ---------------- persistent per-batch recurrent scan ----------------
// One WG per batch element b.  512 threads; thread t owns ru columns {t, t+512} and c column t.
// WhT[k][j] = Wh_ru[j][k] (512x1024), WrhT[k][j] = Wrh_c[j][k] (512x512),
// WxruT[k][j] = Wx_ru[j][k] (256x1024, FUSED fallback only).
// c_x was precomputed into out[b, t, :]; we read it then overwrite with h_t.
template <bool FUSED>
__launch_bounds__(512)
__global__ void gru_scan(const float* __restrict__ input,
                         const float* __restrict__ h0,     // [B, 512]
                         const float* __restrict__ WhT,
                         const float* __restrict__ WrhT,
                         const float* __restrict__ WxruT,
                         const float* __restrict__ ru_x,   // [B*T, 1024] (hoisted mode)
                         float* __restrict__ out)          // hidden [B,T,512] ++ hn [B,512]
{
    const int b = blockIdx.x;
    const int t = threadIdx.x;     // 0..511

    __shared__ float h_lds[H_];
    __shared__ float rh_lds[H_];
    __shared__ float x_lds[I_];

    h_lds[t] = h0[(size_t)b * H_ + t];
    __syncthreads();

    float* hid_b = out + (size_t)b * T_ * H_;
    const float* wr = WhT + t;          // column t of Wh_ru^T view
    const float* wu = WhT + 512 + t;    // column 512+t
    const float* wc = WrhT + t;

    for (int step = 0; step < T_; ++step) {
        float accr, accu;
        if (FUSED) {
            if (t < I_) x_lds[t] = input[((size_t)b * T_ + step) * I_ + t];
            accr = 0.0f;
            accu = 1.0f;                                   // UPDATE_BIAS
        } else {
            const float* rx = ru_x + ((size_t)b * T_ + step) * 1024;
            accr = rx[t];
            accu = rx[512 + t] + 1.0f;                     // UPDATE_BIAS
        }
        if (FUSED) {
            __syncthreads();
            #pragma unroll 8
            for (int k = 0; k < I_; ++k) {
                float xk = x_lds[k];
                accr = fmaf(xk, WxruT[(size_t)k * 1024 + t],       accr);
                accu = fmaf(xk, WxruT[(size_t)k * 1024 + 512 + t], accu);
            }
        }
        // phase 1: ru_h = h @ Wh_ru^T  (streams 2MB from L2)
        #pragma unroll 8
        for (int k = 0; k < H_; ++k) {
            float hk = h_lds[k];
            accr = fmaf(hk, wr[(size_t)k * 1024], accr);
            accu = fmaf(hk, wu[(size_t)k * 1024], accu);
        }
        float r = sigmoidf_(accr);
        float u = sigmoidf_(accu);
        rh_lds[t] = r * h_lds[t];
        __syncthreads();

        // phase 2: c = tanh(c_x + (r*h) @ Wrh_c^T)  (streams 1MB from L2)
        float accc = hid_b[(size_t)step * H_ + t];         // precomputed c_x
        #pragma unroll 8
        for (int k = 0; k < H_; ++k)
            accc = fmaf(rh_lds[k], wc[(size_t)k * 512], accc);
        float c = tanhf(accc);

        float hnew = u * h_lds[t] + (1.0f - u) * c;
        h_lds[t] = hnew;                                   // safe: all threads passed the sync above
        hid_b[(size_t)step * H_ + t] = hnew;               // overwrite c_x slot with h_t
        __syncthreads();
    }
    out[(size_t)B_ * T_ * H_ + (size_t)b * H_ + t] = h_lds[t];   // hn
}

extern "C" void kernel_launch(void* const* d_in, const int* in_sizes, int n_in,
                              void* d_out, int out_size, void* d_ws, size_t ws_size,
                              hipStream_t stream)
{
    const float* x     = (const float*)d_in[0];   // [B,T,I]
    const float* h0    = (const float*)d_in[1];   // [B,H,1]
    const float* Wx_ru = (const float*)d_in[2];   // [1024,256]
    const float* Wx_c  = (const float*)d_in[3];   // [512,256]
    const float* Wh_ru = (const float*)d_in[4];   // [1024,512]
    const float* Wrh_c = (const float*)d_in[5];   // [512,512]
    float* out = (float*)d_out;

    float* wsf   = (float*)d_ws;
    float* WhT   = wsf;                                 // 512*1024
    float* WrhT  = WhT  + 512 * 1024;                   // 512*512
    float* WxruT = WrhT + 512 * 512;                    // 256*1024
    float* ru_x  = WxruT + 256 * 1024;                  // B*T*1024 (hoisted mode)

    const size_t need_hoisted =
        ((size_t)512 * 1024 + 512 * 512 + 256 * 1024 + (size_t)B_ * T_ * 1024) * sizeof(float);
    const bool hoisted = ws_size >= need_hoisted;       // constant per process -> graph-safe branch

    // weight transposes (every call; inputs restored before each timed launch)
    transpose_k<<<dim3(512 / 32, 1024 / 32), 256, 0, stream>>>(Wh_ru, WhT, 1024, 512);
    transpose_k<<<dim3(512 / 32,  512 / 32), 256, 0, stream>>>(Wrh_c, WrhT, 512, 512);
    if (!hoisted)
        transpose_k<<<dim3(256 / 32, 1024 / 32), 256, 0, stream>>>(Wx_ru, WxruT, 1024, 256);

    if (hoisted) {
        proj_gemm<<<dim3(24, (B_ * T_) / BM), 256, 0, stream>>>(x, Wx_ru, Wx_c, ru_x, out, 0);
        gru_scan<false><<<B_, 512, 0, stream>>>(x, h0, WhT, WrhT, WxruT, ru_x, out);
    } else {
        proj_gemm<<<dim3(8, (B_ * T_) / BM), 256, 0, stream>>>(x, Wx_ru, Wx_c, ru_x, out, 1024);
        gru_scan<true><<<B_, 512, 0, stream>>>(x, h0, WhT, WrhT, WxruT, ru_x, out);
    }
}

// Round 3
// 25856.418 us; speedup vs baseline: 1.1239x; 1.1239x over previous
//
#include <hip/hip_runtime.h>
#include <math.h>

// GRU-modified: B=64, T=1024, I=256, H=512, fp32.
// R3: weight-stationary scan, 256 WGs = 8 batch-domains x 32 row-groups, 1 WG/CU.
//  - R2 post-mortem: R2 wrote a 256MB ru_x into ws, but R1's counters prove ws_size < 262MB
//    (FETCH 209MB = fused path) -> OOB -> container death. R3 uses only 263KB of ws.
//  - ru_x projection FUSED into the scan: A-phase dot over k = [h(512); x(256)] = 768 with
//    Wx_ru rows appended to the stationary LDS weight tile. c_x stays hoisted in d_out (R1-proven).
//  - Per-wave vmcnt drain before the domain flag barrier (R2 only drained wave 0).
//  - Bounded spin: deadlock -> visible FAIL, never a hang.

#define B_ 64
#define T_ 1024
#define I_ 256
#define H_ 512

#define NWG   256
#define NDOM  8          // batch domains, 8 batches each
#define DOMWG 32         // WGs per domain barrier
#define BPW   8          // batches per WG

#define HXS   772        // hx row stride: 512 h + 256 x + 4 pad (banks)
#define ACCS  33         // acc per-batch stride

__device__ __forceinline__ float sigmoidf_(float x) { return 1.0f / (1.0f + expf(-x)); }

// ---------------- domain barrier: flag + gen, agent fences, bounded spin ----------------
__device__ __forceinline__ void dom_barrier(unsigned* cnt, unsigned* gen, bool* dead)
{
    asm volatile("s_waitcnt vmcnt(0)" ::: "memory");   // EVERY wave drains its global stores
    __syncthreads();
    if (threadIdx.x == 0 && !*dead) {
        __builtin_amdgcn_fence(__ATOMIC_RELEASE, "agent");   // flush this XCD's L2
        unsigned g = __hip_atomic_load(gen, __ATOMIC_RELAXED, __HIP_MEMORY_SCOPE_AGENT);
        unsigned a = __hip_atomic_fetch_add(cnt, 1u, __ATOMIC_RELAXED, __HIP_MEMORY_SCOPE_AGENT);
        if (a == DOMWG - 1u) {
            __hip_atomic_store(cnt, 0u, __ATOMIC_RELAXED, __HIP_MEMORY_SCOPE_AGENT);
            __hip_atomic_store(gen, g + 1u, __ATOMIC_RELEASE, __HIP_MEMORY_SCOPE_AGENT);
        } else {
            int spins = 0;
            while (__hip_atomic_load(gen, __ATOMIC_RELAXED, __HIP_MEMORY_SCOPE_AGENT) == g) {
                __builtin_amdgcn_s_sleep(2);
                if (++spins > (1 << 17)) { *dead = true; break; }   // ~ms-scale cap: fail visibly
            }
        }
        __builtin_amdgcn_fence(__ATOMIC_ACQUIRE, "agent");   // invalidate L1/L2 before reading peers
    }
    __syncthreads();
}

// ---------------- init: H state from h0, zero barrier flags ----------------
__global__ void init_k(const float* __restrict__ h0, float* __restrict__ Hst,
                       unsigned* __restrict__ flags)
{
    int i = blockIdx.x * 512 + threadIdx.x;
    Hst[i] = h0[i];
    if (blockIdx.x == 0 && threadIdx.x < 256) flags[threadIdx.x] = 0u;
}

// ---------------- c_x projection GEMM (R1-proven core, Wc only) ----------------
#define BM 64
#define BN 64
#define BK 32
__launch_bounds__(256)
__global__ void proj_c(const float* __restrict__ X,
                       const float* __restrict__ Wc,    // [512,256]
                       float* __restrict__ c_x)         // [B*T,512] (= d_out hidden area)
{
    const int ntile = blockIdx.x * BN;                  // 0..448
    const size_t m0 = (size_t)blockIdx.y * BM;

    __shared__ float As[BK][BM + 4];
    __shared__ float Bs[BK][BN + 4];

    const int tid = threadIdx.x;
    const int tx = tid & 15, ty = tid >> 4;
    float acc[4][4] = {};

    for (int k0 = 0; k0 < I_; k0 += BK) {
        #pragma unroll
        for (int lq = 0; lq < 2; ++lq) {
            int q = tid * 2 + lq;
            int r = q >> 3, c4 = (q & 7) * 4;
            float4 v = *(const float4*)(X + (m0 + r) * I_ + k0 + c4);
            As[c4 + 0][r] = v.x; As[c4 + 1][r] = v.y; As[c4 + 2][r] = v.z; As[c4 + 3][r] = v.w;
        }
        #pragma unroll
        for (int lq = 0; lq < 2; ++lq) {
            int q = tid * 2 + lq;
            int n = q >> 3, c4 = (q & 7) * 4;
            float4 v = *(const float4*)(Wc + (size_t)(ntile + n) * I_ + k0 + c4);
            Bs[c4 + 0][n] = v.x; Bs[c4 + 1][n] = v.y; Bs[c4 + 2][n] = v.z; Bs[c4 + 3][n] = v.w;
        }
        __syncthreads();
        #pragma unroll
        for (int kk = 0; kk < BK; ++kk) {
            float4 a = *(const float4*)&As[kk][ty * 4];
            float4 b = *(const float4*)&Bs[kk][tx * 4];
            acc[0][0] += a.x * b.x; acc[0][1] += a.x * b.y; acc[0][2] += a.x * b.z; acc[0][3] += a.x * b.w;
            acc[1][0] += a.y * b.x; acc[1][1] += a.y * b.y; acc[1][2] += a.y * b.z; acc[1][3] += a.y * b.w;
            acc[2][0] += a.z * b.x; acc[2][1] += a.z * b.y; acc[2][2] += a.z * b.z; acc[2][3] += a.z * b.w;
            acc[3][0] += a.w * b.x; acc[3][1] += a.w * b.y; acc[3][2] += a.w * b.z; acc[3][3] += a.w * b.w;
        }
        __syncthreads();
    }
    #pragma unroll
    for (int i = 0; i < 4; ++i) {
        size_t m = m0 + ty * 4 + i;
        float4 v = make_float4(acc[i][0], acc[i][1], acc[i][2], acc[i][3]);
        *(float4*)(c_x + m * 512 + ntile + tx * 4) = v;
    }
}

// ---------------- weight-stationary recurrent scan ----------------
// LDS: wa[768][32] transposed A-weights (rows 0-15: r-gate = Wh_ru[16rg+j] ++ Wx_ru[16rg+j];
//      rows 16-31: u-gate, 512+16rg+j), wc[512][16] transposed Wrh_c rows, hx[8][772] = h ++ x,
//      acc[8][33] cross-wave accumulator (LDS atomicAdd). Total 156,832 B.
__launch_bounds__(512)
__global__ void gru_scan3(const float* __restrict__ Wh_ru,  // [1024,512]
                          const float* __restrict__ Wrh_c,  // [512,512]
                          const float* __restrict__ Wx_ru,  // [1024,256]
                          const float* __restrict__ xin,    // [B,T,256]
                          float* __restrict__ Hst,          // [64,512] (ws)
                          float* __restrict__ RHst,         // [64,512] (ws)
                          unsigned* __restrict__ flags,
                          float* __restrict__ out)          // [B,T,512] ++ hn[B,512]
{
    __shared__ float wa[768 * 32];
    __shared__ float wc[512 * 16];
    __shared__ float hx[BPW * HXS];
    __shared__ float acc[BPW * ACCS];
    __shared__ bool  dead;

    const int wg  = blockIdx.x;
    const int dom = wg >> 5;          // 0..7
    const int rg  = wg & 31;          // 0..31
    const int t   = threadIdx.x;
    const int wv  = t >> 6;           // wave 0..7
    const int l   = t & 63;

    if (t == 0) dead = false;

    // ---- one-time: load transposed stationary weights ----
    {
        int jrow = t >> 4;            // 0..31 (A rows)
        int kc   = t & 15;
        size_t gja = (jrow < 16) ? (size_t)(16 * rg + jrow) : (size_t)(512 + 16 * rg + jrow - 16);
        #pragma unroll
        for (int lp = 0; lp < 12; ++lp) {
            int k = (lp * 16 + kc) * 4;                       // 0..764
            float4 v = (k < 512) ? *(const float4*)(Wh_ru + gja * 512 + k)
                                 : *(const float4*)(Wx_ru + gja * 256 + (k - 512));
            wa[(k + 0) * 32 + jrow] = v.x;
            wa[(k + 1) * 32 + jrow] = v.y;
            wa[(k + 2) * 32 + jrow] = v.z;
            wa[(k + 3) * 32 + jrow] = v.w;
        }
        int jr  = t >> 5;             // 0..15 (C rows)
        int kc2 = t & 31;
        #pragma unroll
        for (int lp = 0; lp < 4; ++lp) {
            int k = (lp * 32 + kc2) * 4;                      // 0..508
            float4 v = *(const float4*)(Wrh_c + (size_t)(16 * rg + jr) * 512 + k);
            wc[(k + 0) * 16 + jr] = v.x;
            wc[(k + 1) * 16 + jr] = v.y;
            wc[(k + 2) * 16 + jr] = v.z;
            wc[(k + 3) * 16 + jr] = v.w;
        }
    }
    if (t < BPW * ACCS) acc[t] = 0.0f;

    unsigned* cnt = flags + dom * 16;
    unsigned* gen = cnt + 8;

    // finalize-thread mapping (t < 128)
    const int fb = t >> 4;                 // 0..7
    const int fj = t & 15;                 // 0..15
    const int gjr = 16 * rg + fj;          // owned hidden index
    const int bglob = dom * BPW + fb;
    float u_reg = 0.f, ho_reg = 0.f, hn_last = 0.f, cx_reg = 0.f;

    __syncthreads();

    for (int step = 0; step < T_; ++step) {
        // prefetch c_x for finalize-B (overlaps with staging + A)
        if (t < 128) cx_reg = out[((size_t)bglob * T_ + step) * H_ + gjr];

        // ---- stage h and x into hx ----
        #pragma unroll
        for (int i = 0; i < 2; ++i) {
            int idx = t + i * 512;          // f4 idx 0..1023
            int b = idx >> 7, kq = (idx & 127) * 4;
            *(float4*)(hx + b * HXS + kq) =
                *(const float4*)(Hst + (size_t)(dom * BPW + b) * H_ + kq);
        }
        {
            int b = t >> 6, kq = (t & 63) * 4;
            *(float4*)(hx + b * HXS + 512 + kq) =
                *(const float4*)(xin + ((size_t)(dom * BPW + b) * T_ + step) * I_ + kq);
        }
        __syncthreads();

        // ---- A microkernel: ru partials over k = [h;x] (768) ----
        {
            const int jq = l & 7, bp = (l >> 3) & 3, kh = l >> 5;
            const int kb = wv * 96 + kh * 48;
            const float* hx0 = hx + (2 * bp) * HXS;
            const float* hx1 = hx0 + HXS;
            float4 a0 = {0, 0, 0, 0}, a1 = {0, 0, 0, 0};
            #pragma unroll
            for (int kk = 0; kk < 12; ++kk) {
                int k = kb + kk * 4;
                float4 w0 = *(const float4*)(wa + (k + 0) * 32 + 4 * jq);
                float4 w1 = *(const float4*)(wa + (k + 1) * 32 + 4 * jq);
                float4 w2 = *(const float4*)(wa + (k + 2) * 32 + 4 * jq);
                float4 w3 = *(const float4*)(wa + (k + 3) * 32 + 4 * jq);
                float4 h0v = *(const float4*)(hx0 + k);
                float4 h1v = *(const float4*)(hx1 + k);
                a0.x = fmaf(w0.x, h0v.x, a0.x); a0.y = fmaf(w0.y, h0v.x, a0.y);
                a0.z = fmaf(w0.z, h0v.x, a0.z); a0.w = fmaf(w0.w, h0v.x, a0.w);
                a0.x = fmaf(w1.x, h0v.y, a0.x); a0.y = fmaf(w1.y, h0v.y, a0.y);
                a0.z = fmaf(w1.z, h0v.y, a0.z); a0.w = fmaf(w1.w, h0v.y, a0.w);
                a0.x = fmaf(w2.x, h0v.z, a0.x); a0.y = fmaf(w2.y, h0v.z, a0.y);
                a0.z = fmaf(w2.z, h0v.z, a0.z); a0.w = fmaf(w2.w, h0v.z, a0.w);
                a0.x = fmaf(w3.x, h0v.w, a0.x); a0.y = fmaf(w3.y, h0v.w, a0.y);
                a0.z = fmaf(w3.z, h0v.w, a0.z); a0.w = fmaf(w3.w, h0v.w, a0.w);
                a1.x = fmaf(w0.x, h1v.x, a1.x); a1.y = fmaf(w0.y, h1v.x, a1.y);
                a1.z = fmaf(w0.z, h1v.x, a1.z); a1.w = fmaf(w0.w, h1v.x, a1.w);
                a1.x = fmaf(w1.x, h1v.y, a1.x); a1.y = fmaf(w1.y, h1v.y, a1.y);
                a1.z = fmaf(w1.z, h1v.y, a1.z); a1.w = fmaf(w1.w, h1v.y, a1.w);
                a1.x = fmaf(w2.x, h1v.z, a1.x); a1.y = fmaf(w2.y, h1v.z, a1.y);
                a1.z = fmaf(w2.z, h1v.z, a1.z); a1.w = fmaf(w2.w, h1v.z, a1.w);
                a1.x = fmaf(w3.x, h1v.w, a1.x); a1.y = fmaf(w3.y, h1v.w, a1.y);
                a1.z = fmaf(w3.z, h1v.w, a1.z); a1.w = fmaf(w3.w, h1v.w, a1.w);
            }
            a0.x += __shfl_xor(a0.x, 32); a0.y += __shfl_xor(a0.y, 32);
            a0.z += __shfl_xor(a0.z, 32); a0.w += __shfl_xor(a0.w, 32);
            a1.x += __shfl_xor(a1.x, 32); a1.y += __shfl_xor(a1.y, 32);
            a1.z += __shfl_xor(a1.z, 32); a1.w += __shfl_xor(a1.w, 32);
            if (kh == 0) {
                float* p0 = acc + (2 * bp) * ACCS + 4 * jq;
                float* p1 = p0 + ACCS;
                atomicAdd(p0 + 0, a0.x); atomicAdd(p0 + 1, a0.y);
                atomicAdd(p0 + 2, a0.z); atomicAdd(p0 + 3, a0.w);
                atomicAdd(p1 + 0, a1.x); atomicAdd(p1 + 1, a1.y);
                atomicAdd(p1 + 2, a1.z); atomicAdd(p1 + 3, a1.w);
            }
        }
        __syncthreads();

        // ---- finalize A: gates, write r*h ----
        if (t < 128) {
            float sr = acc[fb * ACCS + fj];
            float su = acc[fb * ACCS + 16 + fj];
            float r = sigmoidf_(sr);
            u_reg   = sigmoidf_(su + 1.0f);               // UPDATE_BIAS
            ho_reg  = hx[fb * HXS + gjr];
            RHst[(size_t)bglob * H_ + gjr] = r * ho_reg;
        }
        __syncthreads();
        if (t < BPW * ACCS) acc[t] = 0.0f;                // zero for C phase
        dom_barrier(cnt, gen, &dead);

        // ---- stage r*h ----
        #pragma unroll
        for (int i = 0; i < 2; ++i) {
            int idx = t + i * 512;
            int b = idx >> 7, kq = (idx & 127) * 4;
            *(float4*)(hx + b * HXS + kq) =
                *(const float4*)(RHst + (size_t)(dom * BPW + b) * H_ + kq);
        }
        __syncthreads();

        // ---- C microkernel: c partials over k = 512 ----
        {
            const int jq = l & 3, bp = (l >> 2) & 3, kh = l >> 4;
            const int kb = wv * 64 + kh * 16;
            const float* hx0 = hx + (2 * bp) * HXS;
            const float* hx1 = hx0 + HXS;
            float4 a0 = {0, 0, 0, 0}, a1 = {0, 0, 0, 0};
            #pragma unroll
            for (int kk = 0; kk < 4; ++kk) {
                int k = kb + kk * 4;
                float4 w0 = *(const float4*)(wc + (k + 0) * 16 + 4 * jq);
                float4 w1 = *(const float4*)(wc + (k + 1) * 16 + 4 * jq);
                float4 w2 = *(const float4*)(wc + (k + 2) * 16 + 4 * jq);
                float4 w3 = *(const float4*)(wc + (k + 3) * 16 + 4 * jq);
                float4 h0v = *(const float4*)(hx0 + k);
                float4 h1v = *(const float4*)(hx1 + k);
                a0.x = fmaf(w0.x, h0v.x, a0.x); a0.y = fmaf(w0.y, h0v.x, a0.y);
                a0.z = fmaf(w0.z, h0v.x, a0.z); a0.w = fmaf(w0.w, h0v.x, a0.w);
                a0.x = fmaf(w1.x, h0v.y, a0.x); a0.y = fmaf(w1.y, h0v.y, a0.y);
                a0.z = fmaf(w1.z, h0v.y, a0.z); a0.w = fmaf(w1.w, h0v.y, a0.w);
                a0.x = fmaf(w2.x, h0v.z, a0.x); a0.y = fmaf(w2.y, h0v.z, a0.y);
                a0.z = fmaf(w2.z, h0v.z, a0.z); a0.w = fmaf(w2.w, h0v.z, a0.w);
                a0.x = fmaf(w3.x, h0v.w, a0.x); a0.y = fmaf(w3.y, h0v.w, a0.y);
                a0.z = fmaf(w3.z, h0v.w, a0.z); a0.w = fmaf(w3.w, h0v.w, a0.w);
                a1.x = fmaf(w0.x, h1v.x, a1.x); a1.y = fmaf(w0.y, h1v.x, a1.y);
                a1.z = fmaf(w0.z, h1v.x, a1.z); a1.w = fmaf(w0.w, h1v.x, a1.w);
                a1.x = fmaf(w1.x, h1v.y, a1.x); a1.y = fmaf(w1.y, h1v.y, a1.y);
                a1.z = fmaf(w1.z, h1v.y, a1.z); a1.w = fmaf(w1.w, h1v.y, a1.w);
                a1.x = fmaf(w2.x, h1v.z, a1.x); a1.y = fmaf(w2.y, h1v.z, a1.y);
                a1.z = fmaf(w2.z, h1v.z, a1.z); a1.w = fmaf(w2.w, h1v.z, a1.w);
                a1.x = fmaf(w3.x, h1v.w, a1.x); a1.y = fmaf(w3.y, h1v.w, a1.y);
                a1.z = fmaf(w3.z, h1v.w, a1.z); a1.w = fmaf(w3.w, h1v.w, a1.w);
            }
            a0.x += __shfl_xor(a0.x, 16); a0.y += __shfl_xor(a0.y, 16);
            a0.z += __shfl_xor(a0.z, 16); a0.w += __shfl_xor(a0.w, 16);
            a1.x += __shfl_xor(a1.x, 16); a1.y += __shfl_xor(a1.y, 16);
            a1.z += __shfl_xor(a1.z, 16); a1.w += __shfl_xor(a1.w, 16);
            a0.x += __shfl_xor(a0.x, 32); a0.y += __shfl_xor(a0.y, 32);
            a0.z += __shfl_xor(a0.z, 32); a0.w += __shfl_xor(a0.w, 32);
            a1.x += __shfl_xor(a1.x, 32); a1.y += __shfl_xor(a1.y, 32);
            a1.z += __shfl_xor(a1.z, 32); a1.w += __shfl_xor(a1.w, 32);
            if (l < 16) {
                float* p0 = acc + (2 * bp) * ACCS + 4 * jq;
                float* p1 = p0 + ACCS;
                atomicAdd(p0 + 0, a0.x); atomicAdd(p0 + 1, a0.y);
                atomicAdd(p0 + 2, a0.z); atomicAdd(p0 + 3, a0.w);
                atomicAdd(p1 + 0, a1.x); atomicAdd(p1 + 1, a1.y);
                atomicAdd(p1 + 2, a1.z); atomicAdd(p1 + 3, a1.w);
            }
        }
        __syncthreads();

        // ---- finalize B: c, h_new ----
        if (t < 128) {
            float c = tanhf(acc[fb * ACCS + fj] + cx_reg);
            hn_last = u_reg * ho_reg + (1.0f - u_reg) * c;
            Hst[(size_t)bglob * H_ + gjr] = hn_last;
            out[((size_t)bglob * T_ + step) * H_ + gjr] = hn_last;
        }
        __syncthreads();
        if (t < BPW * ACCS) acc[t] = 0.0f;                // zero for next A phase
        dom_barrier(cnt, gen, &dead);
    }

    if (t < 128)
        out[(size_t)B_ * T_ * H_ + (size_t)bglob * H_ + gjr] = hn_last;
}

extern "C" void kernel_launch(void* const* d_in, const int* in_sizes, int n_in,
                              void* d_out, int out_size, void* d_ws, size_t ws_size,
                              hipStream_t stream)
{
    const float* x     = (const float*)d_in[0];
    const float* h0    = (const float*)d_in[1];
    const float* Wx_ru = (const float*)d_in[2];
    const float* Wx_c  = (const float*)d_in[3];
    const float* Wh_ru = (const float*)d_in[4];
    const float* Wrh_c = (const float*)d_in[5];
    float* out = (float*)d_out;

    // workspace: 263 KB total (R1 proved ws_size >= 4 MB)
    unsigned* flags = (unsigned*)d_ws;            // 256 u32
    float* wsf  = (float*)d_ws;
    float* Hst  = wsf + 256;                      // [64][512]
    float* RHst = Hst + B_ * H_;                  // [64][512]

    init_k<<<B_, 512, 0, stream>>>(h0, Hst, flags);
    proj_c<<<dim3(8, (B_ * T_) / BM), 256, 0, stream>>>(x, Wx_c, out);
    gru_scan3<<<NWG, 512, 0, stream>>>(Wh_ru, Wrh_c, Wx_ru, x, Hst, RHst, flags, out);
}

// Round 5
// 15273.453 us; speedup vs baseline: 1.9027x; 1.6929x over previous
//
#include <hip/hip_runtime.h>
#include <math.h>

// GRU-modified: B=64, T=1024, I=256, H=512, fp32.
// R5: fence-free weight-stationary scan (R4 intent, compilable).
//  - R3 post-mortem: agent fences = buffer_wbl2/inv full-L2 flushes, 2048x/step total
//    -> ~20us/step + 1.5GB L2 refill traffic. That was ~75% of runtime.
//  - R4 compile fail: tied 128-bit asm operands unsupported. Fix: NO inline-asm data
//    plane. Cross-WG state (Hst/RHst) via __hip_atomic_load/store RELAXED+AGENT
//    (per-access sc-flagged, L2-bypassing, compiler-correct). No cache fences anywhere.
//  - Ordering: s_waitcnt vmcnt(0) (bare asm, no operands) before barrier arrival;
//    barrier = monotonic per-domain L3 atomic counter; bounded spin -> visible FAIL.
//  - Weights register-resident (96+32 VGPR/lane, persistent across 1024 steps).

#define B_ 64
#define T_ 1024
#define I_ 256
#define H_ 512

#define NWG   256
#define DOMWG 32         // WGs per domain barrier
#define BPW   8          // batches per WG

#define HXS   772        // hx row stride floats: 512 h + 256 x + 4 pad
#define ACCS  33         // accLds per-batch stride

__device__ __forceinline__ float sigmoidf_(float x) { return 1.0f / (1.0f + expf(-x)); }

// ---- coherent data plane: per-access agent-scope (sc-flagged), no fences ----
__device__ __forceinline__ float ld_coh(const float* p)
{
    return __hip_atomic_load(p, __ATOMIC_RELAXED, __HIP_MEMORY_SCOPE_AGENT);
}
__device__ __forceinline__ void st_coh(float* p, float v)
{
    __hip_atomic_store(p, v, __ATOMIC_RELAXED, __HIP_MEMORY_SCOPE_AGENT);
}

// ---- domain barrier: monotonic counter, no fences, bounded spin ----
__device__ __forceinline__ void dom_barrier(unsigned* cnt, unsigned target, bool* dead)
{
    asm volatile("s_waitcnt vmcnt(0)" ::: "memory");   // coherent stores visible pre-arrival
    __syncthreads();
    if (threadIdx.x == 0) {
        __hip_atomic_fetch_add(cnt, 1u, __ATOMIC_RELAXED, __HIP_MEMORY_SCOPE_AGENT);
        if (!*dead) {
            int spins = 0;
            while (__hip_atomic_load(cnt, __ATOMIC_RELAXED, __HIP_MEMORY_SCOPE_AGENT) < target) {
                __builtin_amdgcn_s_sleep(2);
                if (++spins > (1 << 16)) { *dead = true; break; }   // visible FAIL, no hang
            }
        }
    }
    __syncthreads();
}

// ---------------- init: H state from h0, zero barrier counters ----------------
__global__ void init_k(const float* __restrict__ h0, float* __restrict__ Hst,
                       unsigned* __restrict__ flags)
{
    int i = blockIdx.x * 512 + threadIdx.x;
    Hst[i] = h0[i];
    if (blockIdx.x == 0 && threadIdx.x < 256) flags[threadIdx.x] = 0u;
}

// ---------------- c_x projection GEMM (R1/R3-proven core) ----------------
#define BM 64
#define BN 64
#define BK 32
__launch_bounds__(256)
__global__ void proj_c(const float* __restrict__ X,
                       const float* __restrict__ Wc,    // [512,256]
                       float* __restrict__ c_x)         // [B*T,512] (= d_out hidden area)
{
    const int ntile = blockIdx.x * BN;
    const size_t m0 = (size_t)blockIdx.y * BM;

    __shared__ float As[BK][BM + 4];
    __shared__ float Bs[BK][BN + 4];

    const int tid = threadIdx.x;
    const int tx = tid & 15, ty = tid >> 4;
    float acc[4][4] = {};

    for (int k0 = 0; k0 < I_; k0 += BK) {
        #pragma unroll
        for (int lq = 0; lq < 2; ++lq) {
            int q = tid * 2 + lq;
            int r = q >> 3, c4 = (q & 7) * 4;
            float4 v = *(const float4*)(X + (m0 + r) * I_ + k0 + c4);
            As[c4 + 0][r] = v.x; As[c4 + 1][r] = v.y; As[c4 + 2][r] = v.z; As[c4 + 3][r] = v.w;
        }
        #pragma unroll
        for (int lq = 0; lq < 2; ++lq) {
            int q = tid * 2 + lq;
            int n = q >> 3, c4 = (q & 7) * 4;
            float4 v = *(const float4*)(Wc + (size_t)(ntile + n) * I_ + k0 + c4);
            Bs[c4 + 0][n] = v.x; Bs[c4 + 1][n] = v.y; Bs[c4 + 2][n] = v.z; Bs[c4 + 3][n] = v.w;
        }
        __syncthreads();
        #pragma unroll
        for (int kk = 0; kk < BK; ++kk) {
            float4 a = *(const float4*)&As[kk][ty * 4];
            float4 b = *(const float4*)&Bs[kk][tx * 4];
            acc[0][0] += a.x * b.x; acc[0][1] += a.x * b.y; acc[0][2] += a.x * b.z; acc[0][3] += a.x * b.w;
            acc[1][0] += a.y * b.x; acc[1][1] += a.y * b.y; acc[1][2] += a.y * b.z; acc[1][3] += a.y * b.w;
            acc[2][0] += a.z * b.x; acc[2][1] += a.z * b.y; acc[2][2] += a.z * b.z; acc[2][3] += a.z * b.w;
            acc[3][0] += a.w * b.x; acc[3][1] += a.w * b.y; acc[3][2] += a.w * b.z; acc[3][3] += a.w * b.w;
        }
        __syncthreads();
    }
    #pragma unroll
    for (int i = 0; i < 4; ++i) {
        size_t m = m0 + ty * 4 + i;
        float4 v = make_float4(acc[i][0], acc[i][1], acc[i][2], acc[i][3]);
        *(float4*)(c_x + m * 512 + ntile + tx * 4) = v;
    }
}

// ---------------- weight-stationary scan, register-resident weights ----------------
__launch_bounds__(512, 2)
__global__ void gru_scan5(const float* __restrict__ Wh_ru,  // [1024,512]
                          const float* __restrict__ Wrh_c,  // [512,512]
                          const float* __restrict__ Wx_ru,  // [1024,256]
                          const float* __restrict__ xin,    // [B,T,256]
                          float* __restrict__ Hst,          // [64,512] (ws, coherent plane)
                          float* __restrict__ RHst,         // [64,512] (ws, coherent plane)
                          unsigned* __restrict__ flags,
                          float* __restrict__ out)          // [B,T,512] ++ hn[B,512]
{
    __shared__ float hx[BPW * HXS];        // [8][772]: h(512) ++ x(256)
    __shared__ float accLds[BPW * ACCS];   // [8][33]
    __shared__ bool  dead;

    const int wg  = blockIdx.x;
    const int dom = wg >> 5;
    const int rg  = wg & 31;
    const int t   = threadIdx.x;
    const int wv  = t >> 6;
    const int l   = t & 63;

    if (t == 0) dead = false;

    // A-phase lane geometry: j4 rows, batch-quad, 24-wide k-chunk of [h(512);x(256)]
    const int j4    = 4 * (l & 7);
    const int bq4   = 4 * ((l >> 3) & 1);
    const int kbA   = 96 * wv + 24 * ((l >> 4) & 3);
    // C-phase lane geometry: 8-wide k-chunk of h(512)
    const int j4C   = 4 * (l & 3);
    const int bq4C  = 4 * ((l >> 2) & 1);
    const int kbC   = 64 * wv + 8 * (l >> 3);

    // ---- one-time: gather persistent weights into registers ----
    float wA[96];
    #pragma unroll
    for (int kk = 0; kk < 24; ++kk) {
        int k = kbA + kk;
        #pragma unroll
        for (int e = 0; e < 4; ++e) {
            int j = j4 + e;
            int row = (j < 16) ? (16 * rg + j) : (512 + 16 * rg + j - 16);
            wA[kk * 4 + e] = (k < 512) ? Wh_ru[(size_t)row * 512 + k]
                                       : Wx_ru[(size_t)row * 256 + (k - 512)];
        }
    }
    float wC[32];
    #pragma unroll
    for (int kk = 0; kk < 8; ++kk) {
        int k = kbC + kk;
        #pragma unroll
        for (int e = 0; e < 4; ++e)
            wC[kk * 4 + e] = Wrh_c[(size_t)(16 * rg + j4C + e) * 512 + k];
    }

    unsigned* cnt = flags + dom * 32;      // per-domain counter, 128B apart

    // finalize-thread mapping (t < 128)
    const int fb = t >> 4;                 // 0..7
    const int fj = t & 15;                 // 0..15
    const int gjr = 16 * rg + fj;          // owned global hidden index
    const int bglob = dom * BPW + fb;
    float u_reg = 0.f, ho_reg = 0.f, hn_last = 0.f, cx_reg = 0.f;

    // staging geometry: thread t stages 8 consecutive floats of batch (t>>6)
    const int sb = t >> 6;
    const int sk = (t & 63) * 8;

    __syncthreads();

    for (int step = 0; step < T_; ++step) {
        // c_x prefetch (plain cached load; written by prior kernel -> coherent at boundary)
        if (t < 128) cx_reg = out[((size_t)bglob * T_ + step) * H_ + gjr];

        // ---- stage S1: zero acc; h (coherent) + x (plain) -> hx ----
        if (t < BPW * ACCS) accLds[t] = 0.0f;
        {
            const float* src = Hst + (size_t)(dom * BPW + sb) * H_ + sk;
            float v0 = ld_coh(src + 0), v1 = ld_coh(src + 1), v2 = ld_coh(src + 2), v3 = ld_coh(src + 3);
            float v4 = ld_coh(src + 4), v5 = ld_coh(src + 5), v6 = ld_coh(src + 6), v7 = ld_coh(src + 7);
            *(float4*)(hx + sb * HXS + sk)     = make_float4(v0, v1, v2, v3);
            *(float4*)(hx + sb * HXS + sk + 4) = make_float4(v4, v5, v6, v7);
        }
        {
            int kq = (t & 63) * 4;
            *(float4*)(hx + sb * HXS + 512 + kq) =
                *(const float4*)(xin + ((size_t)(dom * BPW + sb) * T_ + step) * I_ + kq);
        }
        __syncthreads();

        // ---- A compute: ru partials over k=[h;x] (768) ----
        {
            float ac[4][4];
            #pragma unroll
            for (int bi = 0; bi < 4; ++bi)
                #pragma unroll
                for (int e = 0; e < 4; ++e) ac[bi][e] = 0.f;
            #pragma unroll
            for (int bi = 0; bi < 4; ++bi) {
                const float* hb = hx + (size_t)(bq4 + bi) * HXS + kbA;
                #pragma unroll
                for (int m = 0; m < 6; ++m) {
                    float4 h4 = *(const float4*)(hb + 4 * m);
                    #pragma unroll
                    for (int e = 0; e < 4; ++e) {
                        ac[bi][e] = fmaf(h4.x, wA[(4 * m + 0) * 4 + e], ac[bi][e]);
                        ac[bi][e] = fmaf(h4.y, wA[(4 * m + 1) * 4 + e], ac[bi][e]);
                        ac[bi][e] = fmaf(h4.z, wA[(4 * m + 2) * 4 + e], ac[bi][e]);
                        ac[bi][e] = fmaf(h4.w, wA[(4 * m + 3) * 4 + e], ac[bi][e]);
                    }
                }
            }
            #pragma unroll
            for (int bi = 0; bi < 4; ++bi)
                #pragma unroll
                for (int e = 0; e < 4; ++e) {
                    float v = ac[bi][e];
                    v += __shfl_xor(v, 16);
                    v += __shfl_xor(v, 32);
                    ac[bi][e] = v;
                }
            if (l < 16) {
                #pragma unroll
                for (int bi = 0; bi < 4; ++bi)
                    #pragma unroll
                    for (int e = 0; e < 4; ++e)
                        atomicAdd(&accLds[(bq4 + bi) * ACCS + j4 + e], ac[bi][e]);
            }
        }
        __syncthreads();

        // ---- finalize A: gates; r*h -> RHst (coherent) ----
        if (t < 128) {
            float sr = accLds[fb * ACCS + fj];
            float su = accLds[fb * ACCS + 16 + fj];
            float r = sigmoidf_(sr);
            u_reg   = sigmoidf_(su + 1.0f);          // UPDATE_BIAS
            ho_reg  = hx[fb * HXS + gjr];
            st_coh(RHst + (size_t)bglob * H_ + gjr, r * ho_reg);
        }
        dom_barrier(cnt, (unsigned)(2 * step + 1) * DOMWG, &dead);

        // ---- stage S2: zero acc; r*h (coherent) -> hx ----
        if (t < BPW * ACCS) accLds[t] = 0.0f;
        {
            const float* src = RHst + (size_t)(dom * BPW + sb) * H_ + sk;
            float v0 = ld_coh(src + 0), v1 = ld_coh(src + 1), v2 = ld_coh(src + 2), v3 = ld_coh(src + 3);
            float v4 = ld_coh(src + 4), v5 = ld_coh(src + 5), v6 = ld_coh(src + 6), v7 = ld_coh(src + 7);
            *(float4*)(hx + sb * HXS + sk)     = make_float4(v0, v1, v2, v3);
            *(float4*)(hx + sb * HXS + sk + 4) = make_float4(v4, v5, v6, v7);
        }
        __syncthreads();

        // ---- C compute: c partials over k=512 ----
        {
            float ac[4][4];
            #pragma unroll
            for (int bi = 0; bi < 4; ++bi)
                #pragma unroll
                for (int e = 0; e < 4; ++e) ac[bi][e] = 0.f;
            #pragma unroll
            for (int bi = 0; bi < 4; ++bi) {
                const float* hb = hx + (size_t)(bq4C + bi) * HXS + kbC;
                #pragma unroll
                for (int m = 0; m < 2; ++m) {
                    float4 h4 = *(const float4*)(hb + 4 * m);
                    #pragma unroll
                    for (int e = 0; e < 4; ++e) {
                        ac[bi][e] = fmaf(h4.x, wC[(4 * m + 0) * 4 + e], ac[bi][e]);
                        ac[bi][e] = fmaf(h4.y, wC[(4 * m + 1) * 4 + e], ac[bi][e]);
                        ac[bi][e] = fmaf(h4.z, wC[(4 * m + 2) * 4 + e], ac[bi][e]);
                        ac[bi][e] = fmaf(h4.w, wC[(4 * m + 3) * 4 + e], ac[bi][e]);
                    }
                }
            }
            #pragma unroll
            for (int bi = 0; bi < 4; ++bi)
                #pragma unroll
                for (int e = 0; e < 4; ++e) {
                    float v = ac[bi][e];
                    v += __shfl_xor(v, 8);
                    v += __shfl_xor(v, 16);
                    v += __shfl_xor(v, 32);
                    ac[bi][e] = v;
                }
            if (l < 8) {
                #pragma unroll
                for (int bi = 0; bi < 4; ++bi)
                    #pragma unroll
                    for (int e = 0; e < 4; ++e)
                        atomicAdd(&accLds[(bq4C + bi) * ACCS + j4C + e], ac[bi][e]);
            }
        }
        __syncthreads();

        // ---- finalize B: c, h_new; Hst (coherent) + hidden out (plain) ----
        if (t < 128) {
            float c = tanhf(accLds[fb * ACCS + fj] + cx_reg);
            hn_last = u_reg * ho_reg + (1.0f - u_reg) * c;
            st_coh(Hst + (size_t)bglob * H_ + gjr, hn_last);
            out[((size_t)bglob * T_ + step) * H_ + gjr] = hn_last;
        }
        dom_barrier(cnt, (unsigned)(2 * step + 2) * DOMWG, &dead);
    }

    if (t < 128)
        out[(size_t)B_ * T_ * H_ + (size_t)bglob * H_ + gjr] = hn_last;
}

extern "C" void kernel_launch(void* const* d_in, const int* in_sizes, int n_in,
                              void* d_out, int out_size, void* d_ws, size_t ws_size,
                              hipStream_t stream)
{
    const float* x     = (const float*)d_in[0];
    const float* h0    = (const float*)d_in[1];
    const float* Wx_ru = (const float*)d_in[2];
    const float* Wx_c  = (const float*)d_in[3];
    const float* Wh_ru = (const float*)d_in[4];
    const float* Wrh_c = (const float*)d_in[5];
    float* out = (float*)d_out;

    // workspace: 263 KB total
    unsigned* flags = (unsigned*)d_ws;            // 256 u32 (8 domains, 128B apart)
    float* wsf  = (float*)d_ws;
    float* Hst  = wsf + 256;                      // [64][512]
    float* RHst = Hst + B_ * H_;                  // [64][512]

    init_k<<<B_, 512, 0, stream>>>(h0, Hst, flags);
    proj_c<<<dim3(8, (B_ * T_) / BM), 256, 0, stream>>>(x, Wx_c, out);
    gru_scan5<<<NWG, 512, 0, stream>>>(Wh_ru, Wrh_c, Wx_ru, x, Hst, RHst, flags, out);
}